// Round 11
// baseline (324.031 us; speedup 1.0000x reference)
//
#include <hip/hip_runtime.h>

// ---------------------------------------------------------------------------
// TransformerBlock: B=2,S=2048,D=768,H=12,DH=64,DFF=3072, causal attn, 2x LN
// Round 11: single-barrier double-buffered GEMM K-loop (BK=32, 2x16KB LDS,
// same 32KB footprint). Loads for tile k+1 issue BEFORE compute of tile k, so
// the compiler's vmcnt(0)-drain at the barrier lands after ~300cyc of MFMA
// work instead of immediately -- hides the exposed load latency that remained
// in the 2-barrier structure. XOR swizzle retained (R10: conflicts 7M->0.4M).
// Attention / split-K plumbing unchanged.
// ---------------------------------------------------------------------------

typedef __attribute__((ext_vector_type(8))) short  short8;   // 8 x bf16 (4 VGPR)
typedef __attribute__((ext_vector_type(4))) float  floatx4;  // 4 x f32 acc

#define QSC 0.18033688f   // 0.125 * log2(e): folded into Q at scatter
#define C2  24.0f         // fixed base-2 softmax offset

__device__ __forceinline__ float b2f(unsigned short u) {
    return __uint_as_float(((unsigned)u) << 16);
}
__device__ __forceinline__ unsigned short f2b(float f) {  // RNE
    unsigned x = __float_as_uint(f);
    return (unsigned short)((x + 0x7fffu + ((x >> 16) & 1u)) >> 16);
}
__device__ __forceinline__ void async_cp16(const void* g, void* l) {
    __builtin_amdgcn_global_load_lds((const __attribute__((address_space(1))) void*)g,
                                     (__attribute__((address_space(3))) void*)l,
                                     16, 0, 0);
}
__device__ __forceinline__ int chunk_ofs(int qb) {
    int t = qb >> 1;
    return (qb & 1) ? (t + 1) * (t + 1) : t * (t + 1);
}
// XOR-swizzled [R][64] bf16 tile (attn): 16B chunk `chunk` of row `row`
__device__ __forceinline__ int swz16(int row, int chunk) {
    return row * 64 + (((chunk ^ (row & 7)) & 7) << 3);
}
// XOR-swizzled [R][32] bf16 tile (gemm BK=32): 4 chunks/row
__device__ __forceinline__ int swz32(int row, int chunk) {
    return row * 32 + (((chunk ^ row) & 3) << 3);
}

// ---------------- fused prepass: x->bf16 + 4 weight transposes --------------
__global__ __launch_bounds__(256) void prep_all(
    const float* __restrict__ x,    unsigned short* __restrict__ xb,
    const float* __restrict__ Wqkv, unsigned short* __restrict__ wqkvT,
    const float* __restrict__ Wout, unsigned short* __restrict__ woutT,
    const float* __restrict__ W1,   unsigned short* __restrict__ w1T,
    const float* __restrict__ W2,   unsigned short* __restrict__ w2T)
{
    __shared__ float tile[32][33];
    int idx = blockIdx.x;
    int tx = threadIdx.x & 31, ty = threadIdx.x >> 5;
    if (idx >= 6912) {  // cvt x
        int i = (idx - 6912) * 256 + threadIdx.x;
        float4 v = ((const float4*)x)[i];
        ushort4 u;
        u.x = f2b(v.x); u.y = f2b(v.y); u.z = f2b(v.z); u.w = f2b(v.w);
        ((ushort4*)xb)[i] = u;
        return;
    }
    const float* W; unsigned short* Wt; int K, N, bx, by;
    if (idx < 1728)      { W = Wqkv; Wt = wqkvT; K = 768;  N = 2304; bx = idx % 72;        by = idx / 72; }
    else if (idx < 2304) { W = Wout; Wt = woutT; K = 768;  N = 768;  bx = (idx-1728) % 24; by = (idx-1728) / 24; }
    else if (idx < 4608) { W = W1;   Wt = w1T;   K = 768;  N = 3072; bx = (idx-2304) % 96; by = (idx-2304) / 96; }
    else                 { W = W2;   Wt = w2T;   K = 3072; N = 768;  bx = (idx-4608) % 24; by = (idx-4608) / 24; }
    int n0 = bx * 32, k0 = by * 32;
    for (int i = ty; i < 32; i += 8)
        tile[i][tx] = W[(size_t)(k0 + i) * N + n0 + tx];
    __syncthreads();
    for (int i = ty; i < 32; i += 8)
        Wt[(size_t)(n0 + i) * K + k0 + tx] = f2b(tile[tx][i]);
}

// ---------------- bf16 MFMA GEMM (BK=32 dbuf, swizzled LDS) ------------------
// mode 0: row-major outF/outB (+bias, relu)
// mode 1: qkv scatter -> outB = Q|K|V each [24][2048][64]; Q scaled by QSC
// mode 2: split-K fp32 partial -> outF + blockIdx.z*M*N
__global__ __launch_bounds__(256) void gemm_bf16(
    const unsigned short* __restrict__ A,
    const unsigned short* __restrict__ Bt,
    const float* __restrict__ bias,
    float* __restrict__ outF,
    unsigned short* __restrict__ outB,
    int M, int N, int K, int relu, int mode, int kslab)
{
    __shared__ unsigned short As[2][4096];   // swizzled [128][32] per buf
    __shared__ unsigned short Bs[2][4096];
    const int tid  = threadIdx.x;
    const int m0   = blockIdx.y * 128;
    const int n0   = blockIdx.x * 128;
    const int kz   = blockIdx.z;
    const int kbeg = kz * kslab;
    const int lane = tid & 63;
    const int wave = tid >> 6;
    const int wm   = (wave >> 1) * 64;
    const int wn   = (wave & 1) * 64;
    const int fr   = lane & 15;
    const int fq   = lane >> 4;
    const int nIt  = kslab >> 5;

    floatx4 acc[4][4];
    for (int i = 0; i < 4; i++)
        for (int j = 0; j < 4; j++)
            for (int e = 0; e < 4; e++) acc[i][j][e] = 0.f;

    // staging: 512 16B-chunks per tensor, 2 per thread
#define STAGE(KK, BUF)                                                         \
    {                                                                          \
        _Pragma("unroll") for (int r_ = 0; r_ < 2; ++r_) {                     \
            int c_   = r_ * 256 + tid;                                         \
            int row_ = c_ >> 2;                                                \
            int jj_  = (((c_ & 3) ^ (row_ & 3)) << 3);                         \
            async_cp16(A  + (size_t)(m0 + row_) * K + (KK) + jj_,              \
                       &As[BUF][c_ * 8]);                                      \
            async_cp16(Bt + (size_t)(n0 + row_) * K + (KK) + jj_,              \
                       &Bs[BUF][c_ * 8]);                                      \
        }                                                                      \
    }

    STAGE(kbeg, 0);
    __syncthreads();

    for (int it = 0; it < nIt; ++it) {
        const int cur = it & 1;
        if (it + 1 < nIt) STAGE(kbeg + (it + 1) * 32, cur ^ 1);  // in flight

        short8 a[4], b[4];
        #pragma unroll
        for (int t = 0; t < 4; t++) a[t] = *(const short8*)&As[cur][swz32(wm + t * 16 + fr, fq)];
        #pragma unroll
        for (int t = 0; t < 4; t++) b[t] = *(const short8*)&Bs[cur][swz32(wn + t * 16 + fr, fq)];
        #pragma unroll
        for (int i = 0; i < 4; i++)
            #pragma unroll
            for (int j = 0; j < 4; j++)
                acc[i][j] = __builtin_amdgcn_mfma_f32_16x16x32_bf16(a[i], b[j], acc[i][j], 0, 0, 0);

        __syncthreads();  // vmcnt(0) drain lands after compute; readers synced
    }
#undef STAGE

    if (mode == 2) {
        float* dst = outF + (size_t)kz * M * N;
        #pragma unroll
        for (int j = 0; j < 4; j++) {
            int col = n0 + wn + j * 16 + fr;
            #pragma unroll
            for (int i = 0; i < 4; i++) {
                int rbase = m0 + wm + i * 16 + fq * 4;
                #pragma unroll
                for (int e = 0; e < 4; e++)
                    dst[(size_t)(rbase + e) * N + col] = acc[i][j][e];
            }
        }
        return;
    }
    if (mode == 1) {
        #pragma unroll
        for (int j = 0; j < 4; j++) {
            int col   = n0 + wn + j * 16 + fr;
            int which = (col >= 1536) ? 2 : (col >= 768 ? 1 : 0);
            float sc  = (which == 0) ? QSC : 1.0f;   // fold 0.125*log2e into Q
            int rem   = col - which * 768;
            int hh    = rem >> 6, d = rem & 63;
            #pragma unroll
            for (int i = 0; i < 4; i++) {
                int rbase = m0 + wm + i * 16 + fq * 4;
                #pragma unroll
                for (int e = 0; e < 4; e++) {
                    int row = rbase + e;
                    int b_  = row >> 11, srow = row & 2047;
                    size_t idx = (size_t)which * 3145728 +
                                 ((size_t)(b_ * 12 + hh) * 2048 + srow) * 64 + d;
                    outB[idx] = f2b(acc[i][j][e] * sc);
                }
            }
        }
        return;
    }
    #pragma unroll
    for (int j = 0; j < 4; j++) {
        int col  = n0 + wn + j * 16 + fr;
        float bv = bias ? bias[col] : 0.f;
        #pragma unroll
        for (int i = 0; i < 4; i++) {
            int rbase = m0 + wm + i * 16 + fq * 4;
            #pragma unroll
            for (int e = 0; e < 4; e++) {
                float v = acc[i][j][e] + bv;
                if (relu) v = fmaxf(v, 0.f);
                size_t idx = (size_t)(rbase + e) * N + col;
                if (outF) outF[idx] = v;
                if (outB) outB[idx] = f2b(v);
            }
        }
    }
}

// ---------------- attention partial (kv-split, lean softmax) ----------------
// Ks/Vt XOR-swizzled; Ps padded stride-72 (affine addresses). l via
// MFMA-with-ones. LDS 51.2KB, 3 blocks/CU.
__global__ __launch_bounds__(256) void attn_part(const unsigned short* __restrict__ Qg,
                                                 const unsigned short* __restrict__ Kg,
                                                 const unsigned short* __restrict__ Vg,
                                                 unsigned short* __restrict__ pO,
                                                 float* __restrict__ pL) {
    __shared__ unsigned short Ks[2][4096];
    __shared__ unsigned short Vt[2][4096];
    __shared__ unsigned short Ps[128 * 72];
    const int tid  = threadIdx.x;
    const int lane = tid & 63;
    const int wave = tid >> 6;
    const int fr   = lane & 15;
    const int fq   = lane >> 4;
    const int wm   = wave * 32;
    const int r    = 71 - blockIdx.x;          // longest chunks first
    const int bh   = blockIdx.y;
    int qb = 0;
    for (int q_ = 15; q_ >= 0; --q_) if (r >= chunk_ofs(q_)) { qb = q_; break; }
    const int c     = r - chunk_ofs(qb);
    const int q0    = qb * 128;
    const int tile0 = 4 * c;
    const int ntk   = min(4, 2 * (qb + 1) - 4 * c);
    const int slot  = bh * 72 + r;
    const unsigned short* Qb = Qg + (size_t)bh * 2048 * 64;
    const unsigned short* Kb = Kg + (size_t)bh * 2048 * 64;
    const unsigned short* Vb = Vg + (size_t)bh * 2048 * 64;

    short8 qf[2][2];
    #pragma unroll
    for (int rf = 0; rf < 2; ++rf) {
        const unsigned short* qr = Qb + (size_t)(q0 + wm + rf * 16 + fr) * 64;
        qf[rf][0] = *(const short8*)(qr + fq * 8);
        qf[rf][1] = *(const short8*)(qr + 32 + fq * 8);
    }

    // all-ones bf16 B fragment for row-sum MFMA
    short8 onesf;
    #pragma unroll
    for (int i = 0; i < 8; ++i) onesf[i] = (short)0x3F80;

    floatx4 o[2][4];
    floatx4 lacc[2];
    #pragma unroll
    for (int rf = 0; rf < 2; ++rf) {
        #pragma unroll
        for (int nt = 0; nt < 4; ++nt)
            #pragma unroll
            for (int e = 0; e < 4; ++e) o[rf][nt][e] = 0.f;
        #pragma unroll
        for (int e = 0; e < 4; ++e) lacc[rf][e] = 0.f;
    }

    const int c0 = tid, c1 = tid + 256;
    uint4 kr0, kr1, vr0, vr1;

#define LOADT(TG)                                                              \
    {                                                                          \
        int base = (TG) * 64;                                                  \
        kr0 = *(const uint4*)(Kb + (size_t)(base + (c0 >> 3)) * 64 + (c0 & 7) * 8); \
        kr1 = *(const uint4*)(Kb + (size_t)(base + (c1 >> 3)) * 64 + (c1 & 7) * 8); \
        vr0 = *(const uint4*)(Vb + (size_t)(base + (c0 & 63)) * 64 + (c0 >> 6) * 8); \
        vr1 = *(const uint4*)(Vb + (size_t)(base + (c1 & 63)) * 64 + (c1 >> 6) * 8); \
    }
// Vt transposed write: row = (c>>6)*8 + i (so row&7 == i), col = c&63
#define WRITET(BUF)                                                            \
    {                                                                          \
        *(uint4*)&Ks[BUF][swz16(c0 >> 3, c0 & 7)] = kr0;                       \
        *(uint4*)&Ks[BUF][swz16(c1 >> 3, c1 & 7)] = kr1;                       \
        unsigned short t0[8]; *(uint4*)t0 = vr0;                               \
        _Pragma("unroll") for (int i_ = 0; i_ < 8; ++i_)                       \
            Vt[BUF][((c0 >> 6) * 8 + i_) * 64 +                                \
                    (((((c0 >> 3) & 7) ^ i_) << 3) | (c0 & 7))] = t0[i_];      \
        unsigned short t1[8]; *(uint4*)t1 = vr1;                               \
        _Pragma("unroll") for (int i_ = 0; i_ < 8; ++i_)                       \
            Vt[BUF][((c1 >> 6) * 8 + i_) * 64 +                                \
                    (((((c1 >> 3) & 7) ^ i_) << 3) | (c1 & 7))] = t1[i_];      \
    }

    LOADT(tile0);
    WRITET(0);
    __syncthreads();

    for (int kt = 0; kt < ntk; ++kt) {
        const int  tg   = tile0 + kt;
        const int  cur  = kt & 1;
        const bool more = (kt + 1 < ntk);
        if (more) LOADT(tg + 1);

        short8 kf[2][4];
        #pragma unroll
        for (int kc = 0; kc < 2; ++kc)
            #pragma unroll
            for (int nt = 0; nt < 4; ++nt)
                kf[kc][nt] = *(const short8*)&Ks[cur][swz16(nt * 16 + fr, kc * 4 + fq)];

        floatx4 s[2][4];
        #pragma unroll
        for (int rf = 0; rf < 2; ++rf)
            #pragma unroll
            for (int nt = 0; nt < 4; ++nt)
                #pragma unroll
                for (int e = 0; e < 4; ++e) s[rf][nt][e] = 0.f;
        #pragma unroll
        for (int rf = 0; rf < 2; ++rf)
            #pragma unroll
            for (int kc = 0; kc < 2; ++kc)
                #pragma unroll
                for (int nt = 0; nt < 4; ++nt)
                    s[rf][nt] = __builtin_amdgcn_mfma_f32_16x16x32_bf16(qf[rf][kc], kf[kc][nt], s[rf][nt], 0, 0, 0);

        // fixed-base softmax: p = 2^(s-C2); masked -> 0.
        const bool need_mask = (tg * 64 + 63) > (q0 + wm);
        #pragma unroll
        for (int rf = 0; rf < 2; ++rf) {
            const int rmin  = q0 + wm + rf * 16;           // min q-row of frag
            const int pbase = (wm + rf * 16 + fq * 4) * 72 + fr;
            #pragma unroll
            for (int nt = 0; nt < 4; ++nt) {
                const bool tmask = need_mask && (tg * 64 + nt * 16 + 15 > rmin);
                const int  kvc   = tg * 64 + nt * 16 + fr;  // this lane's kv col
                #pragma unroll
                for (int e = 0; e < 4; ++e) {
                    float v = s[rf][nt][e] - C2;
                    if (tmask && kvc > rmin + fq * 4 + e) v = -1e30f;
                    float pv = __builtin_amdgcn_exp2f(v);
                    Ps[pbase + e * 72 + nt * 16] =
                        (unsigned short)(__float_as_uint(pv) >> 16);  // trunc
                }
            }
        }
        __asm__ volatile("s_waitcnt lgkmcnt(0)" ::: "memory");  // own-wave P RAW

        short8 pf[2][2], vf[2][4];
        #pragma unroll
        for (int rf = 0; rf < 2; ++rf)
            #pragma unroll
            for (int kc = 0; kc < 2; ++kc)
                pf[rf][kc] = *(const short8*)&Ps[(wm + rf * 16 + fr) * 72 + kc * 32 + fq * 8];
        #pragma unroll
        for (int kc = 0; kc < 2; ++kc)
            #pragma unroll
            for (int nt = 0; nt < 4; ++nt)
                vf[kc][nt] = *(const short8*)&Vt[cur][swz16(nt * 16 + fr, kc * 4 + fq)];
        #pragma unroll
        for (int rf = 0; rf < 2; ++rf)
            #pragma unroll
            for (int kc = 0; kc < 2; ++kc) {
                lacc[rf] = __builtin_amdgcn_mfma_f32_16x16x32_bf16(pf[rf][kc], onesf, lacc[rf], 0, 0, 0);
                #pragma unroll
                for (int nt = 0; nt < 4; ++nt)
                    o[rf][nt] = __builtin_amdgcn_mfma_f32_16x16x32_bf16(pf[rf][kc], vf[kc][nt], o[rf][nt], 0, 0, 0);
            }

        if (more) {
            WRITET(cur ^ 1);
            __syncthreads();
        }
    }
#undef LOADT
#undef WRITET

    #pragma unroll
    for (int rf = 0; rf < 2; ++rf)
        #pragma unroll
        for (int e = 0; e < 4; ++e) {
            int row = wm + rf * 16 + fq * 4 + e;
            unsigned short* orow = pO + ((size_t)slot * 128 + row) * 64;
            #pragma unroll
            for (int nt = 0; nt < 4; ++nt)
                orow[nt * 16 + fr] = f2b(o[rf][nt][e]);
            if (fr == 0)
                pL[(size_t)slot * 128 + row] = lacc[rf][e];
        }
}

// ---------------- attention combine (fixed base: plain sums) ----------------
__global__ __launch_bounds__(256) void attn_combine(const unsigned short* __restrict__ pO,
                                                    const float* __restrict__ pL,
                                                    unsigned short* __restrict__ ctx) {
    const int qb  = blockIdx.x;
    const int bh  = blockIdx.y;
    const int b   = bh / 12, h = bh % 12;
    const int nch = (qb + 2) >> 1;
    const int slot0 = bh * 72 + chunk_ofs(qb);
    const int tid = threadIdx.x;
    const int row = tid >> 1;
    const int col0 = (tid & 1) * 32;

    float L = 0.f;
    for (int i = 0; i < nch; ++i)
        L += pL[(size_t)(slot0 + i) * 128 + row];

    float acc[32];
    #pragma unroll
    for (int j = 0; j < 32; ++j) acc[j] = 0.f;
    for (int i = 0; i < nch; ++i) {
        const unsigned short* p = pO + ((size_t)(slot0 + i) * 128 + row) * 64 + col0;
        #pragma unroll
        for (int v4 = 0; v4 < 4; ++v4) {
            uint4 u = *(const uint4*)(p + v4 * 8);
            unsigned short t[8]; *(uint4*)t = u;
            #pragma unroll
            for (int j = 0; j < 8; ++j) acc[v4 * 8 + j] += b2f(t[j]);
        }
    }
    float inv = 1.f / L;
    unsigned short* orow = ctx + ((size_t)(b * 2048 + qb * 128 + row)) * 768 + h * 64 + col0;
    #pragma unroll
    for (int v4 = 0; v4 < 4; ++v4) {
        unsigned short t[8];
        #pragma unroll
        for (int j = 0; j < 8; ++j) t[j] = f2b(acc[v4 * 8 + j] * inv);
        *(uint4*)(orow + v4 * 8) = *(uint4*)t;
    }
}

// ---------------- fused split-K reduce + bias + residual + LayerNorm --------
__global__ __launch_bounds__(256) void resid_ln2(const float* __restrict__ X,
                                                 const float* __restrict__ P,
                                                 int nsplit,
                                                 const float* __restrict__ bv,
                                                 const float* __restrict__ gain,
                                                 const float* __restrict__ beta,
                                                 float* __restrict__ outF,
                                                 unsigned short* __restrict__ outB) {
    const int row = blockIdx.x;
    const int t   = threadIdx.x;
    const size_t off = (size_t)row * 768;
    float v[3];
    #pragma unroll
    for (int i = 0; i < 3; i++) {
        size_t c = off + t + i * 256;
        float r = X[c] + bv[t + i * 256];
        for (int p = 0; p < nsplit; ++p) r += P[(size_t)p * 3145728 + c];
        v[i] = r;
    }
    float s  = v[0] + v[1] + v[2];
    float s2 = v[0] * v[0] + v[1] * v[1] + v[2] * v[2];
    #pragma unroll
    for (int o2 = 32; o2 > 0; o2 >>= 1) {
        s  += __shfl_down(s,  o2);
        s2 += __shfl_down(s2, o2);
    }
    __shared__ float rs[4], rq[4];
    if ((t & 63) == 0) { rs[t >> 6] = s; rq[t >> 6] = s2; }
    __syncthreads();
    float S    = rs[0] + rs[1] + rs[2] + rs[3];
    float S2   = rq[0] + rq[1] + rq[2] + rq[3];
    float mean = S * (1.0f / 768.0f);
    float var  = S2 * (1.0f / 768.0f) - mean * mean;
    float inv  = rsqrtf(var + 1e-5f);
    #pragma unroll
    for (int i = 0; i < 3; i++) {
        int c   = t + i * 256;
        float y = gain[c] * (v[i] - mean) * inv + beta[c];
        if (outF) outF[off + c] = y;
        if (outB) outB[off + c] = f2b(y);
    }
}

// ---------------------------------------------------------------------------
extern "C" void kernel_launch(void* const* d_in, const int* in_sizes, int n_in,
                              void* d_out, int out_size, void* d_ws, size_t ws_size,
                              hipStream_t stream) {
    const float* x    = (const float*)d_in[0];
    const float* Wqkv = (const float*)d_in[1];
    const float* Wout = (const float*)d_in[2];
    const float* bout = (const float*)d_in[3];
    const float* W1   = (const float*)d_in[4];
    const float* b1   = (const float*)d_in[5];
    const float* W2   = (const float*)d_in[6];
    const float* b2   = (const float*)d_in[7];
    const float* g1   = (const float*)d_in[8];
    const float* be1  = (const float*)d_in[9];
    const float* g2   = (const float*)d_in[10];
    const float* be2  = (const float*)d_in[11];
    float* out = (float*)d_out;

    // workspace layout (bytes), liveness-aliased; peak 83,361,792
    char* ws = (char*)d_ws;
    unsigned short* wqkvT  = (unsigned short*)(ws + 0);         // 3.5M  ->QKV
    unsigned short* woutT  = (unsigned short*)(ws + 3538944);   // 1.2M  ->Wout
    unsigned short* w1T    = (unsigned short*)(ws + 4718592);   // 4.7M  ->W1
    unsigned short* w2T    = (unsigned short*)(ws + 9437184);   // 4.7M  ->W2
    unsigned short* xb     = (unsigned short*)(ws + 14155776);  // 6.3M  ->QKV
    unsigned short* qkvG   = (unsigned short*)(ws + 20447232);  // 18.9M ->attn_part
    unsigned short* Qg     = qkvG;
    unsigned short* Kg     = qkvG + 3145728;
    unsigned short* Vg     = qkvG + 6291456;
    unsigned short* pO     = (unsigned short*)(ws + 39321600);  // 28.3M ->combine
    float*          pL     = (float*)(ws + 67633152);           // 0.9M  ->combine
    unsigned short* ctxb   = (unsigned short*)(ws + 14155776);  // 6.3M  combine->Wout (xb dead)
    float*          WoutP  = (float*)(ws + 39321600);           // 3x12.6M Wout->LN1; ends 77,070,336
    float*          h      = (float*)(ws + 20447232);           // 12.6M LN1->LN2 (qkvG dead)
    unsigned short* hb     = (unsigned short*)(ws + 77070336);  // 6.3M  LN1->W1; ends 83,361,792
    unsigned short* ffb    = (unsigned short*)(ws + 39321600);  // 25.2M W1->W2 (WoutP dead)
    float*          W2P    = (float*)(ws + 64487424);           // 2x12.6M W2->LN2; ends 77,070,336

    // 1) fused prepass
    prep_all<<<9984, 256, 0, stream>>>(x, xb, Wqkv, wqkvT, Wout, woutT, W1, w1T, W2, w2T);
    // 2) QKV projection -> Q/K/V [bh][s][64] bf16 (Q pre-scaled by QSC)
    gemm_bf16<<<dim3(18, 32), 256, 0, stream>>>(xb, wqkvT, nullptr, nullptr, qkvG,
                                                4096, 2304, 768, 0, 1, 768);
    // 3) kv-split flash attention + combine -> ctx bf16
    attn_part<<<dim3(72, 24), 256, 0, stream>>>(Qg, Kg, Vg, pO, pL);
    attn_combine<<<dim3(16, 24), 256, 0, stream>>>(pO, pL, ctxb);
    // 4) out projection, split-K=3 -> fp32 partials
    gemm_bf16<<<dim3(6, 32, 3), 256, 0, stream>>>(ctxb, woutT, nullptr, WoutP, nullptr,
                                                  4096, 768, 768, 0, 2, 256);
    // 5) h = LN(x + sum(WoutP) + bout) -> fp32 + bf16
    resid_ln2<<<4096, 256, 0, stream>>>(x, WoutP, 3, bout, g1, be1, h, hb);
    // 6) ff = relu(h @ W1 + b1) -> bf16
    gemm_bf16<<<dim3(24, 32), 256, 0, stream>>>(hb, w1T, b1, nullptr, ffb,
                                                4096, 3072, 768, 1, 0, 768);
    // 7) ff2 partials = ff @ W2 (split-K=2)
    gemm_bf16<<<dim3(6, 32, 2), 256, 0, stream>>>(ffb, w2T, nullptr, W2P, nullptr,
                                                  4096, 768, 3072, 0, 2, 1536);
    // 8) out = LN(h + sum(W2P) + b2) -> fp32
    resid_ln2<<<4096, 256, 0, stream>>>(h, W2P, 2, b2, g2, be2, out, nullptr);
}

// Round 12
// 313.606 us; speedup vs baseline: 1.0332x; 1.0332x over previous
//
#include <hip/hip_runtime.h>

// ---------------------------------------------------------------------------
// TransformerBlock: B=2,S=2048,D=768,H=12,DH=64,DFF=3072, causal attn, 2x LN
// Round 12: REVERT GEMM to Round-10 structure (BK=64, two-barrier K-loop,
// staging-source XOR swizzle). R11's single-barrier BK=32 dbuf FAILED:
// swz32 gave 4-way conflicts (2.36M) and the vmcnt(0) barrier drain waits on
// same-iteration loads (nothing hidden) at 2x barrier frequency. 308->324 us.
// This file == R10 state (best measured: 308 us).
// ---------------------------------------------------------------------------

typedef __attribute__((ext_vector_type(8))) short  short8;   // 8 x bf16 (4 VGPR)
typedef __attribute__((ext_vector_type(4))) float  floatx4;  // 4 x f32 acc

#define QSC 0.18033688f   // 0.125 * log2(e): folded into Q at scatter
#define C2  24.0f         // fixed base-2 softmax offset

__device__ __forceinline__ float b2f(unsigned short u) {
    return __uint_as_float(((unsigned)u) << 16);
}
__device__ __forceinline__ unsigned short f2b(float f) {  // RNE
    unsigned x = __float_as_uint(f);
    return (unsigned short)((x + 0x7fffu + ((x >> 16) & 1u)) >> 16);
}
__device__ __forceinline__ void async_cp16(const void* g, void* l) {
    __builtin_amdgcn_global_load_lds((const __attribute__((address_space(1))) void*)g,
                                     (__attribute__((address_space(3))) void*)l,
                                     16, 0, 0);
}
__device__ __forceinline__ int chunk_ofs(int qb) {
    int t = qb >> 1;
    return (qb & 1) ? (t + 1) * (t + 1) : t * (t + 1);
}
// XOR-swizzled [R][64] bf16 tile: elem offset of logical 16B chunk `chunk`
__device__ __forceinline__ int swz16(int row, int chunk) {
    return row * 64 + (((chunk ^ (row & 7)) & 7) << 3);
}

// ---------------- fused prepass: x->bf16 + 4 weight transposes --------------
__global__ __launch_bounds__(256) void prep_all(
    const float* __restrict__ x,    unsigned short* __restrict__ xb,
    const float* __restrict__ Wqkv, unsigned short* __restrict__ wqkvT,
    const float* __restrict__ Wout, unsigned short* __restrict__ woutT,
    const float* __restrict__ W1,   unsigned short* __restrict__ w1T,
    const float* __restrict__ W2,   unsigned short* __restrict__ w2T)
{
    __shared__ float tile[32][33];
    int idx = blockIdx.x;
    int tx = threadIdx.x & 31, ty = threadIdx.x >> 5;
    if (idx >= 6912) {  // cvt x
        int i = (idx - 6912) * 256 + threadIdx.x;
        float4 v = ((const float4*)x)[i];
        ushort4 u;
        u.x = f2b(v.x); u.y = f2b(v.y); u.z = f2b(v.z); u.w = f2b(v.w);
        ((ushort4*)xb)[i] = u;
        return;
    }
    const float* W; unsigned short* Wt; int K, N, bx, by;
    if (idx < 1728)      { W = Wqkv; Wt = wqkvT; K = 768;  N = 2304; bx = idx % 72;        by = idx / 72; }
    else if (idx < 2304) { W = Wout; Wt = woutT; K = 768;  N = 768;  bx = (idx-1728) % 24; by = (idx-1728) / 24; }
    else if (idx < 4608) { W = W1;   Wt = w1T;   K = 768;  N = 3072; bx = (idx-2304) % 96; by = (idx-2304) / 96; }
    else                 { W = W2;   Wt = w2T;   K = 3072; N = 768;  bx = (idx-4608) % 24; by = (idx-4608) / 24; }
    int n0 = bx * 32, k0 = by * 32;
    for (int i = ty; i < 32; i += 8)
        tile[i][tx] = W[(size_t)(k0 + i) * N + n0 + tx];
    __syncthreads();
    for (int i = ty; i < 32; i += 8)
        Wt[(size_t)(n0 + i) * K + k0 + tx] = f2b(tile[tx][i]);
}

// ---------------- bf16 MFMA GEMM (BK=64, swizzled LDS) -----------------------
// mode 0: row-major outF/outB (+bias, relu)
// mode 1: qkv scatter -> outB = Q|K|V each [24][2048][64]; Q scaled by QSC
// mode 2: split-K fp32 partial -> outF + blockIdx.z*M*N
__global__ __launch_bounds__(256) void gemm_bf16(
    const unsigned short* __restrict__ A,
    const unsigned short* __restrict__ Bt,
    const float* __restrict__ bias,
    float* __restrict__ outF,
    unsigned short* __restrict__ outB,
    int M, int N, int K, int relu, int mode, int kslab)
{
    __shared__ unsigned short As[8192];   // swizzled [128][64]
    __shared__ unsigned short Bs[8192];
    const int tid  = threadIdx.x;
    const int m0   = blockIdx.y * 128;
    const int n0   = blockIdx.x * 128;
    const int kz   = blockIdx.z;
    const int kbeg = kz * kslab;
    const int kend = kbeg + kslab;
    const int lane = tid & 63;
    const int wave = tid >> 6;
    const int wm   = (wave >> 1) * 64;
    const int wn   = (wave & 1) * 64;
    const int fr   = lane & 15;
    const int fq   = lane >> 4;

    floatx4 acc[4][4];
    for (int i = 0; i < 4; i++)
        for (int j = 0; j < 4; j++)
            for (int e = 0; e < 4; e++) acc[i][j][e] = 0.f;

    for (int kk = kbeg; kk < kend; kk += 64) {
        __syncthreads();
        #pragma unroll
        for (int r = 0; r < 4; ++r) {
            int c   = r * 256 + tid;          // LDS dest chunk (lane-contig)
            int row = c >> 3;
            int jj  = ((c & 7) ^ (row & 7)) * 8;  // swizzled global source col
            async_cp16(A  + (size_t)(m0 + row) * K + kk + jj, &As[c * 8]);
            async_cp16(Bt + (size_t)(n0 + row) * K + kk + jj, &Bs[c * 8]);
        }
        __syncthreads();

        #pragma unroll
        for (int kc = 0; kc < 2; ++kc) {
            short8 a[4], b[4];
            #pragma unroll
            for (int t = 0; t < 4; t++) a[t] = *(const short8*)&As[swz16(wm + t * 16 + fr, kc * 4 + fq)];
            #pragma unroll
            for (int t = 0; t < 4; t++) b[t] = *(const short8*)&Bs[swz16(wn + t * 16 + fr, kc * 4 + fq)];
            #pragma unroll
            for (int i = 0; i < 4; i++)
                #pragma unroll
                for (int j = 0; j < 4; j++)
                    acc[i][j] = __builtin_amdgcn_mfma_f32_16x16x32_bf16(a[i], b[j], acc[i][j], 0, 0, 0);
        }
    }

    if (mode == 2) {
        float* dst = outF + (size_t)kz * M * N;
        #pragma unroll
        for (int j = 0; j < 4; j++) {
            int col = n0 + wn + j * 16 + fr;
            #pragma unroll
            for (int i = 0; i < 4; i++) {
                int rbase = m0 + wm + i * 16 + fq * 4;
                #pragma unroll
                for (int e = 0; e < 4; e++)
                    dst[(size_t)(rbase + e) * N + col] = acc[i][j][e];
            }
        }
        return;
    }
    if (mode == 1) {
        #pragma unroll
        for (int j = 0; j < 4; j++) {
            int col   = n0 + wn + j * 16 + fr;
            int which = (col >= 1536) ? 2 : (col >= 768 ? 1 : 0);
            float sc  = (which == 0) ? QSC : 1.0f;   // fold 0.125*log2e into Q
            int rem   = col - which * 768;
            int hh    = rem >> 6, d = rem & 63;
            #pragma unroll
            for (int i = 0; i < 4; i++) {
                int rbase = m0 + wm + i * 16 + fq * 4;
                #pragma unroll
                for (int e = 0; e < 4; e++) {
                    int row = rbase + e;
                    int b_  = row >> 11, srow = row & 2047;
                    size_t idx = (size_t)which * 3145728 +
                                 ((size_t)(b_ * 12 + hh) * 2048 + srow) * 64 + d;
                    outB[idx] = f2b(acc[i][j][e] * sc);
                }
            }
        }
        return;
    }
    #pragma unroll
    for (int j = 0; j < 4; j++) {
        int col  = n0 + wn + j * 16 + fr;
        float bv = bias ? bias[col] : 0.f;
        #pragma unroll
        for (int i = 0; i < 4; i++) {
            int rbase = m0 + wm + i * 16 + fq * 4;
            #pragma unroll
            for (int e = 0; e < 4; e++) {
                float v = acc[i][j][e] + bv;
                if (relu) v = fmaxf(v, 0.f);
                size_t idx = (size_t)(rbase + e) * N + col;
                if (outF) outF[idx] = v;
                if (outB) outB[idx] = f2b(v);
            }
        }
    }
}

// ---------------- attention partial (kv-split, lean softmax) ----------------
// Ks/Vt XOR-swizzled; Ps padded stride-72 (affine addresses). l via
// MFMA-with-ones. LDS 51.2KB, 3 blocks/CU.
__global__ __launch_bounds__(256) void attn_part(const unsigned short* __restrict__ Qg,
                                                 const unsigned short* __restrict__ Kg,
                                                 const unsigned short* __restrict__ Vg,
                                                 unsigned short* __restrict__ pO,
                                                 float* __restrict__ pL) {
    __shared__ unsigned short Ks[2][4096];
    __shared__ unsigned short Vt[2][4096];
    __shared__ unsigned short Ps[128 * 72];
    const int tid  = threadIdx.x;
    const int lane = tid & 63;
    const int wave = tid >> 6;
    const int fr   = lane & 15;
    const int fq   = lane >> 4;
    const int wm   = wave * 32;
    const int r    = 71 - blockIdx.x;          // longest chunks first
    const int bh   = blockIdx.y;
    int qb = 0;
    for (int q_ = 15; q_ >= 0; --q_) if (r >= chunk_ofs(q_)) { qb = q_; break; }
    const int c     = r - chunk_ofs(qb);
    const int q0    = qb * 128;
    const int tile0 = 4 * c;
    const int ntk   = min(4, 2 * (qb + 1) - 4 * c);
    const int slot  = bh * 72 + r;
    const unsigned short* Qb = Qg + (size_t)bh * 2048 * 64;
    const unsigned short* Kb = Kg + (size_t)bh * 2048 * 64;
    const unsigned short* Vb = Vg + (size_t)bh * 2048 * 64;

    short8 qf[2][2];
    #pragma unroll
    for (int rf = 0; rf < 2; ++rf) {
        const unsigned short* qr = Qb + (size_t)(q0 + wm + rf * 16 + fr) * 64;
        qf[rf][0] = *(const short8*)(qr + fq * 8);
        qf[rf][1] = *(const short8*)(qr + 32 + fq * 8);
    }

    // all-ones bf16 B fragment for row-sum MFMA
    short8 onesf;
    #pragma unroll
    for (int i = 0; i < 8; ++i) onesf[i] = (short)0x3F80;

    floatx4 o[2][4];
    floatx4 lacc[2];
    #pragma unroll
    for (int rf = 0; rf < 2; ++rf) {
        #pragma unroll
        for (int nt = 0; nt < 4; ++nt)
            #pragma unroll
            for (int e = 0; e < 4; ++e) o[rf][nt][e] = 0.f;
        #pragma unroll
        for (int e = 0; e < 4; ++e) lacc[rf][e] = 0.f;
    }

    const int c0 = tid, c1 = tid + 256;
    uint4 kr0, kr1, vr0, vr1;

#define LOADT(TG)                                                              \
    {                                                                          \
        int base = (TG) * 64;                                                  \
        kr0 = *(const uint4*)(Kb + (size_t)(base + (c0 >> 3)) * 64 + (c0 & 7) * 8); \
        kr1 = *(const uint4*)(Kb + (size_t)(base + (c1 >> 3)) * 64 + (c1 & 7) * 8); \
        vr0 = *(const uint4*)(Vb + (size_t)(base + (c0 & 63)) * 64 + (c0 >> 6) * 8); \
        vr1 = *(const uint4*)(Vb + (size_t)(base + (c1 & 63)) * 64 + (c1 >> 6) * 8); \
    }
// Vt transposed write: row = (c>>6)*8 + i (so row&7 == i), col = c&63
#define WRITET(BUF)                                                            \
    {                                                                          \
        *(uint4*)&Ks[BUF][swz16(c0 >> 3, c0 & 7)] = kr0;                       \
        *(uint4*)&Ks[BUF][swz16(c1 >> 3, c1 & 7)] = kr1;                       \
        unsigned short t0[8]; *(uint4*)t0 = vr0;                               \
        _Pragma("unroll") for (int i_ = 0; i_ < 8; ++i_)                       \
            Vt[BUF][((c0 >> 6) * 8 + i_) * 64 +                                \
                    (((((c0 >> 3) & 7) ^ i_) << 3) | (c0 & 7))] = t0[i_];      \
        unsigned short t1[8]; *(uint4*)t1 = vr1;                               \
        _Pragma("unroll") for (int i_ = 0; i_ < 8; ++i_)                       \
            Vt[BUF][((c1 >> 6) * 8 + i_) * 64 +                                \
                    (((((c1 >> 3) & 7) ^ i_) << 3) | (c1 & 7))] = t1[i_];      \
    }

    LOADT(tile0);
    WRITET(0);
    __syncthreads();

    for (int kt = 0; kt < ntk; ++kt) {
        const int  tg   = tile0 + kt;
        const int  cur  = kt & 1;
        const bool more = (kt + 1 < ntk);
        if (more) LOADT(tg + 1);

        short8 kf[2][4];
        #pragma unroll
        for (int kc = 0; kc < 2; ++kc)
            #pragma unroll
            for (int nt = 0; nt < 4; ++nt)
                kf[kc][nt] = *(const short8*)&Ks[cur][swz16(nt * 16 + fr, kc * 4 + fq)];

        floatx4 s[2][4];
        #pragma unroll
        for (int rf = 0; rf < 2; ++rf)
            #pragma unroll
            for (int nt = 0; nt < 4; ++nt)
                #pragma unroll
                for (int e = 0; e < 4; ++e) s[rf][nt][e] = 0.f;
        #pragma unroll
        for (int rf = 0; rf < 2; ++rf)
            #pragma unroll
            for (int kc = 0; kc < 2; ++kc)
                #pragma unroll
                for (int nt = 0; nt < 4; ++nt)
                    s[rf][nt] = __builtin_amdgcn_mfma_f32_16x16x32_bf16(qf[rf][kc], kf[kc][nt], s[rf][nt], 0, 0, 0);

        // fixed-base softmax: p = 2^(s-C2); masked -> 0.
        const bool need_mask = (tg * 64 + 63) > (q0 + wm);
        #pragma unroll
        for (int rf = 0; rf < 2; ++rf) {
            const int rmin  = q0 + wm + rf * 16;           // min q-row of frag
            const int pbase = (wm + rf * 16 + fq * 4) * 72 + fr;
            #pragma unroll
            for (int nt = 0; nt < 4; ++nt) {
                const bool tmask = need_mask && (tg * 64 + nt * 16 + 15 > rmin);
                const int  kvc   = tg * 64 + nt * 16 + fr;  // this lane's kv col
                #pragma unroll
                for (int e = 0; e < 4; ++e) {
                    float v = s[rf][nt][e] - C2;
                    if (tmask && kvc > rmin + fq * 4 + e) v = -1e30f;
                    float pv = __builtin_amdgcn_exp2f(v);
                    Ps[pbase + e * 72 + nt * 16] =
                        (unsigned short)(__float_as_uint(pv) >> 16);  // trunc
                }
            }
        }
        __asm__ volatile("s_waitcnt lgkmcnt(0)" ::: "memory");  // own-wave P RAW

        short8 pf[2][2], vf[2][4];
        #pragma unroll
        for (int rf = 0; rf < 2; ++rf)
            #pragma unroll
            for (int kc = 0; kc < 2; ++kc)
                pf[rf][kc] = *(const short8*)&Ps[(wm + rf * 16 + fr) * 72 + kc * 32 + fq * 8];
        #pragma unroll
        for (int kc = 0; kc < 2; ++kc)
            #pragma unroll
            for (int nt = 0; nt < 4; ++nt)
                vf[kc][nt] = *(const short8*)&Vt[cur][swz16(nt * 16 + fr, kc * 4 + fq)];
        #pragma unroll
        for (int rf = 0; rf < 2; ++rf)
            #pragma unroll
            for (int kc = 0; kc < 2; ++kc) {
                lacc[rf] = __builtin_amdgcn_mfma_f32_16x16x32_bf16(pf[rf][kc], onesf, lacc[rf], 0, 0, 0);
                #pragma unroll
                for (int nt = 0; nt < 4; ++nt)
                    o[rf][nt] = __builtin_amdgcn_mfma_f32_16x16x32_bf16(pf[rf][kc], vf[kc][nt], o[rf][nt], 0, 0, 0);
            }

        if (more) {
            WRITET(cur ^ 1);
            __syncthreads();
        }
    }
#undef LOADT
#undef WRITET

    #pragma unroll
    for (int rf = 0; rf < 2; ++rf)
        #pragma unroll
        for (int e = 0; e < 4; ++e) {
            int row = wm + rf * 16 + fq * 4 + e;
            unsigned short* orow = pO + ((size_t)slot * 128 + row) * 64;
            #pragma unroll
            for (int nt = 0; nt < 4; ++nt)
                orow[nt * 16 + fr] = f2b(o[rf][nt][e]);
            if (fr == 0)
                pL[(size_t)slot * 128 + row] = lacc[rf][e];
        }
}

// ---------------- attention combine (fixed base: plain sums) ----------------
__global__ __launch_bounds__(256) void attn_combine(const unsigned short* __restrict__ pO,
                                                    const float* __restrict__ pL,
                                                    unsigned short* __restrict__ ctx) {
    const int qb  = blockIdx.x;
    const int bh  = blockIdx.y;
    const int b   = bh / 12, h = bh % 12;
    const int nch = (qb + 2) >> 1;
    const int slot0 = bh * 72 + chunk_ofs(qb);
    const int tid = threadIdx.x;
    const int row = tid >> 1;
    const int col0 = (tid & 1) * 32;

    float L = 0.f;
    for (int i = 0; i < nch; ++i)
        L += pL[(size_t)(slot0 + i) * 128 + row];

    float acc[32];
    #pragma unroll
    for (int j = 0; j < 32; ++j) acc[j] = 0.f;
    for (int i = 0; i < nch; ++i) {
        const unsigned short* p = pO + ((size_t)(slot0 + i) * 128 + row) * 64 + col0;
        #pragma unroll
        for (int v4 = 0; v4 < 4; ++v4) {
            uint4 u = *(const uint4*)(p + v4 * 8);
            unsigned short t[8]; *(uint4*)t = u;
            #pragma unroll
            for (int j = 0; j < 8; ++j) acc[v4 * 8 + j] += b2f(t[j]);
        }
    }
    float inv = 1.f / L;
    unsigned short* orow = ctx + ((size_t)(b * 2048 + qb * 128 + row)) * 768 + h * 64 + col0;
    #pragma unroll
    for (int v4 = 0; v4 < 4; ++v4) {
        unsigned short t[8];
        #pragma unroll
        for (int j = 0; j < 8; ++j) t[j] = f2b(acc[v4 * 8 + j] * inv);
        *(uint4*)(orow + v4 * 8) = *(uint4*)t;
    }
}

// ---------------- fused split-K reduce + bias + residual + LayerNorm --------
__global__ __launch_bounds__(256) void resid_ln2(const float* __restrict__ X,
                                                 const float* __restrict__ P,
                                                 int nsplit,
                                                 const float* __restrict__ bv,
                                                 const float* __restrict__ gain,
                                                 const float* __restrict__ beta,
                                                 float* __restrict__ outF,
                                                 unsigned short* __restrict__ outB) {
    const int row = blockIdx.x;
    const int t   = threadIdx.x;
    const size_t off = (size_t)row * 768;
    float v[3];
    #pragma unroll
    for (int i = 0; i < 3; i++) {
        size_t c = off + t + i * 256;
        float r = X[c] + bv[t + i * 256];
        for (int p = 0; p < nsplit; ++p) r += P[(size_t)p * 3145728 + c];
        v[i] = r;
    }
    float s  = v[0] + v[1] + v[2];
    float s2 = v[0] * v[0] + v[1] * v[1] + v[2] * v[2];
    #pragma unroll
    for (int o2 = 32; o2 > 0; o2 >>= 1) {
        s  += __shfl_down(s,  o2);
        s2 += __shfl_down(s2, o2);
    }
    __shared__ float rs[4], rq[4];
    if ((t & 63) == 0) { rs[t >> 6] = s; rq[t >> 6] = s2; }
    __syncthreads();
    float S    = rs[0] + rs[1] + rs[2] + rs[3];
    float S2   = rq[0] + rq[1] + rq[2] + rq[3];
    float mean = S * (1.0f / 768.0f);
    float var  = S2 * (1.0f / 768.0f) - mean * mean;
    float inv  = rsqrtf(var + 1e-5f);
    #pragma unroll
    for (int i = 0; i < 3; i++) {
        int c   = t + i * 256;
        float y = gain[c] * (v[i] - mean) * inv + beta[c];
        if (outF) outF[off + c] = y;
        if (outB) outB[off + c] = f2b(y);
    }
}

// ---------------------------------------------------------------------------
extern "C" void kernel_launch(void* const* d_in, const int* in_sizes, int n_in,
                              void* d_out, int out_size, void* d_ws, size_t ws_size,
                              hipStream_t stream) {
    const float* x    = (const float*)d_in[0];
    const float* Wqkv = (const float*)d_in[1];
    const float* Wout = (const float*)d_in[2];
    const float* bout = (const float*)d_in[3];
    const float* W1   = (const float*)d_in[4];
    const float* b1   = (const float*)d_in[5];
    const float* W2   = (const float*)d_in[6];
    const float* b2   = (const float*)d_in[7];
    const float* g1   = (const float*)d_in[8];
    const float* be1  = (const float*)d_in[9];
    const float* g2   = (const float*)d_in[10];
    const float* be2  = (const float*)d_in[11];
    float* out = (float*)d_out;

    // workspace layout (bytes), liveness-aliased; peak 83,361,792
    char* ws = (char*)d_ws;
    unsigned short* wqkvT  = (unsigned short*)(ws + 0);         // 3.5M  ->QKV
    unsigned short* woutT  = (unsigned short*)(ws + 3538944);   // 1.2M  ->Wout
    unsigned short* w1T    = (unsigned short*)(ws + 4718592);   // 4.7M  ->W1
    unsigned short* w2T    = (unsigned short*)(ws + 9437184);   // 4.7M  ->W2
    unsigned short* xb     = (unsigned short*)(ws + 14155776);  // 6.3M  ->QKV
    unsigned short* qkvG   = (unsigned short*)(ws + 20447232);  // 18.9M ->attn_part
    unsigned short* Qg     = qkvG;
    unsigned short* Kg     = qkvG + 3145728;
    unsigned short* Vg     = qkvG + 6291456;
    unsigned short* pO     = (unsigned short*)(ws + 39321600);  // 28.3M ->combine
    float*          pL     = (float*)(ws + 67633152);           // 0.9M  ->combine
    unsigned short* ctxb   = (unsigned short*)(ws + 14155776);  // 6.3M  combine->Wout (xb dead)
    float*          WoutP  = (float*)(ws + 39321600);           // 3x12.6M Wout->LN1; ends 77,070,336
    float*          h      = (float*)(ws + 20447232);           // 12.6M LN1->LN2 (qkvG dead)
    unsigned short* hb     = (unsigned short*)(ws + 77070336);  // 6.3M  LN1->W1; ends 83,361,792
    unsigned short* ffb    = (unsigned short*)(ws + 39321600);  // 25.2M W1->W2 (WoutP dead)
    float*          W2P    = (float*)(ws + 64487424);           // 2x12.6M W2->LN2; ends 77,070,336

    // 1) fused prepass
    prep_all<<<9984, 256, 0, stream>>>(x, xb, Wqkv, wqkvT, Wout, woutT, W1, w1T, W2, w2T);
    // 2) QKV projection -> Q/K/V [bh][s][64] bf16 (Q pre-scaled by QSC)
    gemm_bf16<<<dim3(18, 32), 256, 0, stream>>>(xb, wqkvT, nullptr, nullptr, qkvG,
                                                4096, 2304, 768, 0, 1, 768);
    // 3) kv-split flash attention + combine -> ctx bf16
    attn_part<<<dim3(72, 24), 256, 0, stream>>>(Qg, Kg, Vg, pO, pL);
    attn_combine<<<dim3(16, 24), 256, 0, stream>>>(pO, pL, ctxb);
    // 4) out projection, split-K=3 -> fp32 partials
    gemm_bf16<<<dim3(6, 32, 3), 256, 0, stream>>>(ctxb, woutT, nullptr, WoutP, nullptr,
                                                  4096, 768, 768, 0, 2, 256);
    // 5) h = LN(x + sum(WoutP) + bout) -> fp32 + bf16
    resid_ln2<<<4096, 256, 0, stream>>>(x, WoutP, 3, bout, g1, be1, h, hb);
    // 6) ff = relu(h @ W1 + b1) -> bf16
    gemm_bf16<<<dim3(24, 32), 256, 0, stream>>>(hb, w1T, b1, nullptr, ffb,
                                                4096, 3072, 768, 1, 0, 768);
    // 7) ff2 partials = ff @ W2 (split-K=2)
    gemm_bf16<<<dim3(6, 32, 2), 256, 0, stream>>>(ffb, w2T, nullptr, W2P, nullptr,
                                                  4096, 768, 3072, 0, 2, 1536);
    // 8) out = LN(h + sum(W2P) + b2) -> fp32
    resid_ln2<<<4096, 256, 0, stream>>>(h, W2P, 2, b2, g2, be2, out, nullptr);
}

// Round 13
// 305.747 us; speedup vs baseline: 1.0598x; 1.0257x over previous
//
#include <hip/hip_runtime.h>

// ---------------------------------------------------------------------------
// TransformerBlock: B=2,S=2048,D=768,H=12,DH=64,DFF=3072, causal attn, 2x LN
// Round 13: attn kv-chunk 256 -> 512 (8 tiles/block, 1728 -> 960 blocks).
// Amortizes per-block startup (Q load, first-KV latency, epilogue drain) 2x,
// halves pO/pL partial traffic (28.3 -> 15.7 MB each way). GEMM = R10 proven
// structure (BK=64, two barriers, staging-source XOR swizzle).
// ---------------------------------------------------------------------------

typedef __attribute__((ext_vector_type(8))) short  short8;   // 8 x bf16 (4 VGPR)
typedef __attribute__((ext_vector_type(4))) float  floatx4;  // 4 x f32 acc

#define QSC 0.18033688f   // 0.125 * log2(e): folded into Q at scatter
#define C2  24.0f         // fixed base-2 softmax offset

__device__ __forceinline__ float b2f(unsigned short u) {
    return __uint_as_float(((unsigned)u) << 16);
}
__device__ __forceinline__ unsigned short f2b(float f) {  // RNE
    unsigned x = __float_as_uint(f);
    return (unsigned short)((x + 0x7fffu + ((x >> 16) & 1u)) >> 16);
}
__device__ __forceinline__ void async_cp16(const void* g, void* l) {
    __builtin_amdgcn_global_load_lds((const __attribute__((address_space(1))) void*)g,
                                     (__attribute__((address_space(3))) void*)l,
                                     16, 0, 0);
}
// chunk-slot prefix for 512-wide kv chunks: ofs(qb) = sum_{j<qb} ceil((j+1)/4)
//   = (t+1)*(2t+rem), t = qb>>2, rem = qb&3.  ofs(16) = 40 slots per bh.
__device__ __forceinline__ int chunk_ofs8(int qb) {
    int t = qb >> 2, rem = qb & 3;
    return (t + 1) * (2 * t + rem);
}
// XOR-swizzled [R][64] bf16 tile: elem offset of logical 16B chunk `chunk`
__device__ __forceinline__ int swz16(int row, int chunk) {
    return row * 64 + (((chunk ^ (row & 7)) & 7) << 3);
}

// ---------------- fused prepass: x->bf16 + 4 weight transposes --------------
__global__ __launch_bounds__(256) void prep_all(
    const float* __restrict__ x,    unsigned short* __restrict__ xb,
    const float* __restrict__ Wqkv, unsigned short* __restrict__ wqkvT,
    const float* __restrict__ Wout, unsigned short* __restrict__ woutT,
    const float* __restrict__ W1,   unsigned short* __restrict__ w1T,
    const float* __restrict__ W2,   unsigned short* __restrict__ w2T)
{
    __shared__ float tile[32][33];
    int idx = blockIdx.x;
    int tx = threadIdx.x & 31, ty = threadIdx.x >> 5;
    if (idx >= 6912) {  // cvt x
        int i = (idx - 6912) * 256 + threadIdx.x;
        float4 v = ((const float4*)x)[i];
        ushort4 u;
        u.x = f2b(v.x); u.y = f2b(v.y); u.z = f2b(v.z); u.w = f2b(v.w);
        ((ushort4*)xb)[i] = u;
        return;
    }
    const float* W; unsigned short* Wt; int K, N, bx, by;
    if (idx < 1728)      { W = Wqkv; Wt = wqkvT; K = 768;  N = 2304; bx = idx % 72;        by = idx / 72; }
    else if (idx < 2304) { W = Wout; Wt = woutT; K = 768;  N = 768;  bx = (idx-1728) % 24; by = (idx-1728) / 24; }
    else if (idx < 4608) { W = W1;   Wt = w1T;   K = 768;  N = 3072; bx = (idx-2304) % 96; by = (idx-2304) / 96; }
    else                 { W = W2;   Wt = w2T;   K = 3072; N = 768;  bx = (idx-4608) % 24; by = (idx-4608) / 24; }
    int n0 = bx * 32, k0 = by * 32;
    for (int i = ty; i < 32; i += 8)
        tile[i][tx] = W[(size_t)(k0 + i) * N + n0 + tx];
    __syncthreads();
    for (int i = ty; i < 32; i += 8)
        Wt[(size_t)(n0 + i) * K + k0 + tx] = f2b(tile[tx][i]);
}

// ---------------- bf16 MFMA GEMM (BK=64, swizzled LDS) -----------------------
// mode 0: row-major outF/outB (+bias, relu)
// mode 1: qkv scatter -> outB = Q|K|V each [24][2048][64]; Q scaled by QSC
// mode 2: split-K fp32 partial -> outF + blockIdx.z*M*N
__global__ __launch_bounds__(256) void gemm_bf16(
    const unsigned short* __restrict__ A,
    const unsigned short* __restrict__ Bt,
    const float* __restrict__ bias,
    float* __restrict__ outF,
    unsigned short* __restrict__ outB,
    int M, int N, int K, int relu, int mode, int kslab)
{
    __shared__ unsigned short As[8192];   // swizzled [128][64]
    __shared__ unsigned short Bs[8192];
    const int tid  = threadIdx.x;
    const int m0   = blockIdx.y * 128;
    const int n0   = blockIdx.x * 128;
    const int kz   = blockIdx.z;
    const int kbeg = kz * kslab;
    const int kend = kbeg + kslab;
    const int lane = tid & 63;
    const int wave = tid >> 6;
    const int wm   = (wave >> 1) * 64;
    const int wn   = (wave & 1) * 64;
    const int fr   = lane & 15;
    const int fq   = lane >> 4;

    floatx4 acc[4][4];
    for (int i = 0; i < 4; i++)
        for (int j = 0; j < 4; j++)
            for (int e = 0; e < 4; e++) acc[i][j][e] = 0.f;

    for (int kk = kbeg; kk < kend; kk += 64) {
        __syncthreads();
        #pragma unroll
        for (int r = 0; r < 4; ++r) {
            int c   = r * 256 + tid;          // LDS dest chunk (lane-contig)
            int row = c >> 3;
            int jj  = ((c & 7) ^ (row & 7)) * 8;  // swizzled global source col
            async_cp16(A  + (size_t)(m0 + row) * K + kk + jj, &As[c * 8]);
            async_cp16(Bt + (size_t)(n0 + row) * K + kk + jj, &Bs[c * 8]);
        }
        __syncthreads();

        #pragma unroll
        for (int kc = 0; kc < 2; ++kc) {
            short8 a[4], b[4];
            #pragma unroll
            for (int t = 0; t < 4; t++) a[t] = *(const short8*)&As[swz16(wm + t * 16 + fr, kc * 4 + fq)];
            #pragma unroll
            for (int t = 0; t < 4; t++) b[t] = *(const short8*)&Bs[swz16(wn + t * 16 + fr, kc * 4 + fq)];
            #pragma unroll
            for (int i = 0; i < 4; i++)
                #pragma unroll
                for (int j = 0; j < 4; j++)
                    acc[i][j] = __builtin_amdgcn_mfma_f32_16x16x32_bf16(a[i], b[j], acc[i][j], 0, 0, 0);
        }
    }

    if (mode == 2) {
        float* dst = outF + (size_t)kz * M * N;
        #pragma unroll
        for (int j = 0; j < 4; j++) {
            int col = n0 + wn + j * 16 + fr;
            #pragma unroll
            for (int i = 0; i < 4; i++) {
                int rbase = m0 + wm + i * 16 + fq * 4;
                #pragma unroll
                for (int e = 0; e < 4; e++)
                    dst[(size_t)(rbase + e) * N + col] = acc[i][j][e];
            }
        }
        return;
    }
    if (mode == 1) {
        #pragma unroll
        for (int j = 0; j < 4; j++) {
            int col   = n0 + wn + j * 16 + fr;
            int which = (col >= 1536) ? 2 : (col >= 768 ? 1 : 0);
            float sc  = (which == 0) ? QSC : 1.0f;   // fold 0.125*log2e into Q
            int rem   = col - which * 768;
            int hh    = rem >> 6, d = rem & 63;
            #pragma unroll
            for (int i = 0; i < 4; i++) {
                int rbase = m0 + wm + i * 16 + fq * 4;
                #pragma unroll
                for (int e = 0; e < 4; e++) {
                    int row = rbase + e;
                    int b_  = row >> 11, srow = row & 2047;
                    size_t idx = (size_t)which * 3145728 +
                                 ((size_t)(b_ * 12 + hh) * 2048 + srow) * 64 + d;
                    outB[idx] = f2b(acc[i][j][e] * sc);
                }
            }
        }
        return;
    }
    #pragma unroll
    for (int j = 0; j < 4; j++) {
        int col  = n0 + wn + j * 16 + fr;
        float bv = bias ? bias[col] : 0.f;
        #pragma unroll
        for (int i = 0; i < 4; i++) {
            int rbase = m0 + wm + i * 16 + fq * 4;
            #pragma unroll
            for (int e = 0; e < 4; e++) {
                float v = acc[i][j][e] + bv;
                if (relu) v = fmaxf(v, 0.f);
                size_t idx = (size_t)(rbase + e) * N + col;
                if (outF) outF[idx] = v;
                if (outB) outB[idx] = f2b(v);
            }
        }
    }
}

// ---------------- attention partial (512-wide kv chunks) --------------------
// grid (40, 24): slot r in [0,40) per bh; qb s.t. ofs8(qb) <= r < ofs8(qb+1),
// c = r - ofs8(qb). Tiles [8c, min(8c+8, 2qb+2)). Ks/Vt XOR-swizzled, Ps
// stride-72 affine, l via MFMA-with-ones. LDS 51.2KB, 3 blocks/CU.
__global__ __launch_bounds__(256) void attn_part(const unsigned short* __restrict__ Qg,
                                                 const unsigned short* __restrict__ Kg,
                                                 const unsigned short* __restrict__ Vg,
                                                 unsigned short* __restrict__ pO,
                                                 float* __restrict__ pL) {
    __shared__ unsigned short Ks[2][4096];
    __shared__ unsigned short Vt[2][4096];
    __shared__ unsigned short Ps[128 * 72];
    const int tid  = threadIdx.x;
    const int lane = tid & 63;
    const int wave = tid >> 6;
    const int fr   = lane & 15;
    const int fq   = lane >> 4;
    const int wm   = wave * 32;
    const int r    = 39 - blockIdx.x;          // longest chunks first
    const int bh   = blockIdx.y;
    int qb = 0;
    for (int q_ = 15; q_ >= 0; --q_) if (r >= chunk_ofs8(q_)) { qb = q_; break; }
    const int c     = r - chunk_ofs8(qb);
    const int q0    = qb * 128;
    const int tile0 = 8 * c;
    const int ntk   = min(8, 2 * (qb + 1) - 8 * c);
    const int slot  = bh * 40 + r;
    const unsigned short* Qb = Qg + (size_t)bh * 2048 * 64;
    const unsigned short* Kb = Kg + (size_t)bh * 2048 * 64;
    const unsigned short* Vb = Vg + (size_t)bh * 2048 * 64;

    short8 qf[2][2];
    #pragma unroll
    for (int rf = 0; rf < 2; ++rf) {
        const unsigned short* qr = Qb + (size_t)(q0 + wm + rf * 16 + fr) * 64;
        qf[rf][0] = *(const short8*)(qr + fq * 8);
        qf[rf][1] = *(const short8*)(qr + 32 + fq * 8);
    }

    // all-ones bf16 B fragment for row-sum MFMA
    short8 onesf;
    #pragma unroll
    for (int i = 0; i < 8; ++i) onesf[i] = (short)0x3F80;

    floatx4 o[2][4];
    floatx4 lacc[2];
    #pragma unroll
    for (int rf = 0; rf < 2; ++rf) {
        #pragma unroll
        for (int nt = 0; nt < 4; ++nt)
            #pragma unroll
            for (int e = 0; e < 4; ++e) o[rf][nt][e] = 0.f;
        #pragma unroll
        for (int e = 0; e < 4; ++e) lacc[rf][e] = 0.f;
    }

    const int c0 = tid, c1 = tid + 256;
    uint4 kr0, kr1, vr0, vr1;

#define LOADT(TG)                                                              \
    {                                                                          \
        int base = (TG) * 64;                                                  \
        kr0 = *(const uint4*)(Kb + (size_t)(base + (c0 >> 3)) * 64 + (c0 & 7) * 8); \
        kr1 = *(const uint4*)(Kb + (size_t)(base + (c1 >> 3)) * 64 + (c1 & 7) * 8); \
        vr0 = *(const uint4*)(Vb + (size_t)(base + (c0 & 63)) * 64 + (c0 >> 6) * 8); \
        vr1 = *(const uint4*)(Vb + (size_t)(base + (c1 & 63)) * 64 + (c1 >> 6) * 8); \
    }
// Vt transposed write: row = (c>>6)*8 + i (so row&7 == i), col = c&63
#define WRITET(BUF)                                                            \
    {                                                                          \
        *(uint4*)&Ks[BUF][swz16(c0 >> 3, c0 & 7)] = kr0;                       \
        *(uint4*)&Ks[BUF][swz16(c1 >> 3, c1 & 7)] = kr1;                       \
        unsigned short t0[8]; *(uint4*)t0 = vr0;                               \
        _Pragma("unroll") for (int i_ = 0; i_ < 8; ++i_)                       \
            Vt[BUF][((c0 >> 6) * 8 + i_) * 64 +                                \
                    (((((c0 >> 3) & 7) ^ i_) << 3) | (c0 & 7))] = t0[i_];      \
        unsigned short t1[8]; *(uint4*)t1 = vr1;                               \
        _Pragma("unroll") for (int i_ = 0; i_ < 8; ++i_)                       \
            Vt[BUF][((c1 >> 6) * 8 + i_) * 64 +                                \
                    (((((c1 >> 3) & 7) ^ i_) << 3) | (c1 & 7))] = t1[i_];      \
    }

    LOADT(tile0);
    WRITET(0);
    __syncthreads();

    for (int kt = 0; kt < ntk; ++kt) {
        const int  tg   = tile0 + kt;
        const int  cur  = kt & 1;
        const bool more = (kt + 1 < ntk);
        if (more) LOADT(tg + 1);

        short8 kf[2][4];
        #pragma unroll
        for (int kc = 0; kc < 2; ++kc)
            #pragma unroll
            for (int nt = 0; nt < 4; ++nt)
                kf[kc][nt] = *(const short8*)&Ks[cur][swz16(nt * 16 + fr, kc * 4 + fq)];

        floatx4 s[2][4];
        #pragma unroll
        for (int rf = 0; rf < 2; ++rf)
            #pragma unroll
            for (int nt = 0; nt < 4; ++nt)
                #pragma unroll
                for (int e = 0; e < 4; ++e) s[rf][nt][e] = 0.f;
        #pragma unroll
        for (int rf = 0; rf < 2; ++rf)
            #pragma unroll
            for (int kc = 0; kc < 2; ++kc)
                #pragma unroll
                for (int nt = 0; nt < 4; ++nt)
                    s[rf][nt] = __builtin_amdgcn_mfma_f32_16x16x32_bf16(qf[rf][kc], kf[kc][nt], s[rf][nt], 0, 0, 0);

        // fixed-base softmax: p = 2^(s-C2); masked -> 0.
        const bool need_mask = (tg * 64 + 63) > (q0 + wm);
        #pragma unroll
        for (int rf = 0; rf < 2; ++rf) {
            const int rmin  = q0 + wm + rf * 16;           // min q-row of frag
            const int pbase = (wm + rf * 16 + fq * 4) * 72 + fr;
            #pragma unroll
            for (int nt = 0; nt < 4; ++nt) {
                const bool tmask = need_mask && (tg * 64 + nt * 16 + 15 > rmin);
                const int  kvc   = tg * 64 + nt * 16 + fr;  // this lane's kv col
                #pragma unroll
                for (int e = 0; e < 4; ++e) {
                    float v = s[rf][nt][e] - C2;
                    if (tmask && kvc > rmin + fq * 4 + e) v = -1e30f;
                    float pv = __builtin_amdgcn_exp2f(v);
                    Ps[pbase + e * 72 + nt * 16] =
                        (unsigned short)(__float_as_uint(pv) >> 16);  // trunc
                }
            }
        }
        __asm__ volatile("s_waitcnt lgkmcnt(0)" ::: "memory");  // own-wave P RAW

        short8 pf[2][2], vf[2][4];
        #pragma unroll
        for (int rf = 0; rf < 2; ++rf)
            #pragma unroll
            for (int kc = 0; kc < 2; ++kc)
                pf[rf][kc] = *(const short8*)&Ps[(wm + rf * 16 + fr) * 72 + kc * 32 + fq * 8];
        #pragma unroll
        for (int kc = 0; kc < 2; ++kc)
            #pragma unroll
            for (int nt = 0; nt < 4; ++nt)
                vf[kc][nt] = *(const short8*)&Vt[cur][swz16(nt * 16 + fr, kc * 4 + fq)];
        #pragma unroll
        for (int rf = 0; rf < 2; ++rf)
            #pragma unroll
            for (int kc = 0; kc < 2; ++kc) {
                lacc[rf] = __builtin_amdgcn_mfma_f32_16x16x32_bf16(pf[rf][kc], onesf, lacc[rf], 0, 0, 0);
                #pragma unroll
                for (int nt = 0; nt < 4; ++nt)
                    o[rf][nt] = __builtin_amdgcn_mfma_f32_16x16x32_bf16(pf[rf][kc], vf[kc][nt], o[rf][nt], 0, 0, 0);
            }

        if (more) {
            WRITET(cur ^ 1);
            __syncthreads();
        }
    }
#undef LOADT
#undef WRITET

    #pragma unroll
    for (int rf = 0; rf < 2; ++rf)
        #pragma unroll
        for (int e = 0; e < 4; ++e) {
            int row = wm + rf * 16 + fq * 4 + e;
            unsigned short* orow = pO + ((size_t)slot * 128 + row) * 64;
            #pragma unroll
            for (int nt = 0; nt < 4; ++nt)
                orow[nt * 16 + fr] = f2b(o[rf][nt][e]);
            if (fr == 0)
                pL[(size_t)slot * 128 + row] = lacc[rf][e];
        }
}

// ---------------- attention combine (fixed base: plain sums) ----------------
// grid (16, 24); merges <=4 chunks of 512 kv each.
__global__ __launch_bounds__(256) void attn_combine(const unsigned short* __restrict__ pO,
                                                    const float* __restrict__ pL,
                                                    unsigned short* __restrict__ ctx) {
    const int qb  = blockIdx.x;
    const int bh  = blockIdx.y;
    const int b   = bh / 12, h = bh % 12;
    const int nch = (qb >> 2) + 1;             // ceil((qb+1)/4)
    const int slot0 = bh * 40 + chunk_ofs8(qb);
    const int tid = threadIdx.x;
    const int row = tid >> 1;
    const int col0 = (tid & 1) * 32;

    float L = 0.f;
    for (int i = 0; i < nch; ++i)
        L += pL[(size_t)(slot0 + i) * 128 + row];

    float acc[32];
    #pragma unroll
    for (int j = 0; j < 32; ++j) acc[j] = 0.f;
    for (int i = 0; i < nch; ++i) {
        const unsigned short* p = pO + ((size_t)(slot0 + i) * 128 + row) * 64 + col0;
        #pragma unroll
        for (int v4 = 0; v4 < 4; ++v4) {
            uint4 u = *(const uint4*)(p + v4 * 8);
            unsigned short t[8]; *(uint4*)t = u;
            #pragma unroll
            for (int j = 0; j < 8; ++j) acc[v4 * 8 + j] += b2f(t[j]);
        }
    }
    float inv = 1.f / L;
    unsigned short* orow = ctx + ((size_t)(b * 2048 + qb * 128 + row)) * 768 + h * 64 + col0;
    #pragma unroll
    for (int v4 = 0; v4 < 4; ++v4) {
        unsigned short t[8];
        #pragma unroll
        for (int j = 0; j < 8; ++j) t[j] = f2b(acc[v4 * 8 + j] * inv);
        *(uint4*)(orow + v4 * 8) = *(uint4*)t;
    }
}

// ---------------- fused split-K reduce + bias + residual + LayerNorm --------
__global__ __launch_bounds__(256) void resid_ln2(const float* __restrict__ X,
                                                 const float* __restrict__ P,
                                                 int nsplit,
                                                 const float* __restrict__ bv,
                                                 const float* __restrict__ gain,
                                                 const float* __restrict__ beta,
                                                 float* __restrict__ outF,
                                                 unsigned short* __restrict__ outB) {
    const int row = blockIdx.x;
    const int t   = threadIdx.x;
    const size_t off = (size_t)row * 768;
    float v[3];
    #pragma unroll
    for (int i = 0; i < 3; i++) {
        size_t c = off + t + i * 256;
        float r = X[c] + bv[t + i * 256];
        for (int p = 0; p < nsplit; ++p) r += P[(size_t)p * 3145728 + c];
        v[i] = r;
    }
    float s  = v[0] + v[1] + v[2];
    float s2 = v[0] * v[0] + v[1] * v[1] + v[2] * v[2];
    #pragma unroll
    for (int o2 = 32; o2 > 0; o2 >>= 1) {
        s  += __shfl_down(s,  o2);
        s2 += __shfl_down(s2, o2);
    }
    __shared__ float rs[4], rq[4];
    if ((t & 63) == 0) { rs[t >> 6] = s; rq[t >> 6] = s2; }
    __syncthreads();
    float S    = rs[0] + rs[1] + rs[2] + rs[3];
    float S2   = rq[0] + rq[1] + rq[2] + rq[3];
    float mean = S * (1.0f / 768.0f);
    float var  = S2 * (1.0f / 768.0f) - mean * mean;
    float inv  = rsqrtf(var + 1e-5f);
    #pragma unroll
    for (int i = 0; i < 3; i++) {
        int c   = t + i * 256;
        float y = gain[c] * (v[i] - mean) * inv + beta[c];
        if (outF) outF[off + c] = y;
        if (outB) outB[off + c] = f2b(y);
    }
}

// ---------------------------------------------------------------------------
extern "C" void kernel_launch(void* const* d_in, const int* in_sizes, int n_in,
                              void* d_out, int out_size, void* d_ws, size_t ws_size,
                              hipStream_t stream) {
    const float* x    = (const float*)d_in[0];
    const float* Wqkv = (const float*)d_in[1];
    const float* Wout = (const float*)d_in[2];
    const float* bout = (const float*)d_in[3];
    const float* W1   = (const float*)d_in[4];
    const float* b1   = (const float*)d_in[5];
    const float* W2   = (const float*)d_in[6];
    const float* b2   = (const float*)d_in[7];
    const float* g1   = (const float*)d_in[8];
    const float* be1  = (const float*)d_in[9];
    const float* g2   = (const float*)d_in[10];
    const float* be2  = (const float*)d_in[11];
    float* out = (float*)d_out;

    // workspace layout (bytes), liveness-aliased; peak 83,361,792
    char* ws = (char*)d_ws;
    unsigned short* wqkvT  = (unsigned short*)(ws + 0);         // 3.5M  ->QKV
    unsigned short* woutT  = (unsigned short*)(ws + 3538944);   // 1.2M  ->Wout
    unsigned short* w1T    = (unsigned short*)(ws + 4718592);   // 4.7M  ->W1
    unsigned short* w2T    = (unsigned short*)(ws + 9437184);   // 4.7M  ->W2
    unsigned short* xb     = (unsigned short*)(ws + 14155776);  // 6.3M  ->QKV
    unsigned short* qkvG   = (unsigned short*)(ws + 20447232);  // 18.9M ->attn_part
    unsigned short* Qg     = qkvG;
    unsigned short* Kg     = qkvG + 3145728;
    unsigned short* Vg     = qkvG + 6291456;
    unsigned short* pO     = (unsigned short*)(ws + 39321600);  // 15.7M ->combine (960 slots)
    float*          pL     = (float*)(ws + 67633152);           // 0.49M ->combine
    unsigned short* ctxb   = (unsigned short*)(ws + 14155776);  // 6.3M  combine->Wout (xb dead)
    float*          WoutP  = (float*)(ws + 39321600);           // 3x12.6M Wout->LN1; ends 77,070,336
    float*          h      = (float*)(ws + 20447232);           // 12.6M LN1->LN2 (qkvG dead)
    unsigned short* hb     = (unsigned short*)(ws + 77070336);  // 6.3M  LN1->W1; ends 83,361,792
    unsigned short* ffb    = (unsigned short*)(ws + 39321600);  // 25.2M W1->W2 (WoutP dead)
    float*          W2P    = (float*)(ws + 64487424);           // 2x12.6M W2->LN2; ends 77,070,336

    // 1) fused prepass
    prep_all<<<9984, 256, 0, stream>>>(x, xb, Wqkv, wqkvT, Wout, woutT, W1, w1T, W2, w2T);
    // 2) QKV projection -> Q/K/V [bh][s][64] bf16 (Q pre-scaled by QSC)
    gemm_bf16<<<dim3(18, 32), 256, 0, stream>>>(xb, wqkvT, nullptr, nullptr, qkvG,
                                                4096, 2304, 768, 0, 1, 768);
    // 3) kv-split flash attention (512-wide chunks) + combine -> ctx bf16
    attn_part<<<dim3(40, 24), 256, 0, stream>>>(Qg, Kg, Vg, pO, pL);
    attn_combine<<<dim3(16, 24), 256, 0, stream>>>(pO, pL, ctxb);
    // 4) out projection, split-K=3 -> fp32 partials
    gemm_bf16<<<dim3(6, 32, 3), 256, 0, stream>>>(ctxb, woutT, nullptr, WoutP, nullptr,
                                                  4096, 768, 768, 0, 2, 256);
    // 5) h = LN(x + sum(WoutP) + bout) -> fp32 + bf16
    resid_ln2<<<4096, 256, 0, stream>>>(x, WoutP, 3, bout, g1, be1, h, hb);
    // 6) ff = relu(h @ W1 + b1) -> bf16
    gemm_bf16<<<dim3(24, 32), 256, 0, stream>>>(hb, w1T, b1, nullptr, ffb,
                                                4096, 3072, 768, 1, 0, 768);
    // 7) ff2 partials = ff @ W2 (split-K=2)
    gemm_bf16<<<dim3(6, 32, 2), 256, 0, stream>>>(ffb, w2T, nullptr, W2P, nullptr,
                                                  4096, 768, 3072, 0, 2, 1536);
    // 8) out = LN(h + sum(W2P) + b2) -> fp32
    resid_ln2<<<4096, 256, 0, stream>>>(h, W2P, 2, b2, g2, be2, out, nullptr);
}